// Round 1
// baseline (10328.809 us; speedup 1.0000x reference)
//
#include <hip/hip_runtime.h>

#define NUM_USERS 100000
#define NUM_ITEMS 200000
#define NT        300000        // NUM_USERS + NUM_ITEMS
#define D         64
#define DV4       16            // D / 4
#define NNZ_C     4000000
#define BATCH     16384

// ---------------------------------------------------------------------------
// init: x[r, :] = concat(user_emb_w, item_emb_w)[r, :]   (float4 vectorized)
// ---------------------------------------------------------------------------
__global__ void init_x(const float* __restrict__ uw, const float* __restrict__ iw,
                       float* __restrict__ x) {
    const long total = (long)NT * DV4;                    // 4.8M float4
    const long stride = (long)gridDim.x * blockDim.x;
    for (long i = (long)blockIdx.x * blockDim.x + threadIdx.x; i < total; i += stride) {
        long r = i >> 4;
        long c = i & 15;
        const float4* src = (r < NUM_USERS)
            ? (const float4*)uw + r * DV4 + c
            : (const float4*)iw + (r - NUM_USERS) * DV4 + c;
        ((float4*)x)[i] = *src;
    }
}

// ---------------------------------------------------------------------------
// spmm: y += A x  (COO scatter).  16 threads per edge, float4 per thread.
// A wave's 64 lanes cover 4 consecutive edges -> gathers are 4 x 256B rows.
// ---------------------------------------------------------------------------
__global__ void spmm(const int* __restrict__ row, const int* __restrict__ col,
                     const float* __restrict__ val, const float* __restrict__ x,
                     float* __restrict__ y) {
    const long total = (long)NNZ_C * 16;
    const long stride = (long)gridDim.x * blockDim.x;
    for (long t = (long)blockIdx.x * blockDim.x + threadIdx.x; t < total; t += stride) {
        long e   = t >> 4;
        int  sub = (int)(t & 15);
        int  r   = row[e];
        int  c   = col[e];
        float v  = val[e];
        float4 g = *(const float4*)(x + (long)c * D + sub * 4);
        float* yp = y + (long)r * D + sub * 4;
        unsafeAtomicAdd(yp + 0, g.x * v);
        unsafeAtomicAdd(yp + 1, g.y * v);
        unsafeAtomicAdd(yp + 2, g.z * v);
        unsafeAtomicAdd(yp + 3, g.w * v);
    }
}

// ---------------------------------------------------------------------------
// gather_acc: accumulate this layer's x at only the 2*BATCH needed rows.
// acc layout: [2*BATCH, 64]; b < BATCH -> user row, else item row.
// ---------------------------------------------------------------------------
template <bool FIRST>
__global__ void gather_acc(const int* __restrict__ uid, const int* __restrict__ iid,
                           const float* __restrict__ x, float* __restrict__ acc) {
    int t = blockIdx.x * blockDim.x + threadIdx.x;      // exact launch: 2*BATCH*16
    int b   = t >> 4;
    int sub = t & 15;
    int r   = (b < BATCH) ? uid[b] : (iid[b - BATCH] + NUM_USERS);
    float4 g = *(const float4*)(x + (long)r * D + sub * 4);
    float4* a = (float4*)(acc + (long)b * D) + sub;
    if (FIRST) {
        *a = g;
    } else {
        float4 p = *a;
        p.x += g.x; p.y += g.y; p.z += g.z; p.w += g.w;
        *a = p;
    }
}

// ---------------------------------------------------------------------------
// final: out[b] = dot(accU[b], accI[b]) / 16   (final = acc/4 on both sides)
// 16 lanes per b, float4 per lane, shfl_xor reduction within 16-lane groups.
// ---------------------------------------------------------------------------
__global__ void final_dot(const float* __restrict__ acc, float* __restrict__ out) {
    int t = blockIdx.x * blockDim.x + threadIdx.x;      // exact launch: BATCH*16
    int b   = t >> 4;
    int sub = t & 15;
    float4 u = *((const float4*)(acc + (long)b * D) + sub);
    float4 w = *((const float4*)(acc + (long)(b + BATCH) * D) + sub);
    float p = u.x * w.x + u.y * w.y + u.z * w.z + u.w * w.w;
    p += __shfl_xor(p, 1);
    p += __shfl_xor(p, 2);
    p += __shfl_xor(p, 4);
    p += __shfl_xor(p, 8);
    if (sub == 0) out[b] = p * (1.0f / 16.0f);
}

extern "C" void kernel_launch(void* const* d_in, const int* in_sizes, int n_in,
                              void* d_out, int out_size, void* d_ws, size_t ws_size,
                              hipStream_t stream) {
    const int*   user_ids = (const int*)d_in[0];
    const int*   item_ids = (const int*)d_in[1];
    const int*   adj_row  = (const int*)d_in[2];
    const int*   adj_col  = (const int*)d_in[3];
    const float* adj_val  = (const float*)d_in[4];
    const float* uw       = (const float*)d_in[5];
    const float* iw       = (const float*)d_in[6];
    float*       out      = (float*)d_out;

    char* ws = (char*)d_ws;
    const size_t xbytes = (size_t)NT * D * sizeof(float);   // 76.8 MB
    float* xA  = (float*)ws;
    float* xB  = (float*)(ws + xbytes);
    float* acc = (float*)(ws + 2 * xbytes);                 // [2*BATCH, 64] = 8.4 MB

    // x0 = concat(user_emb_w, item_emb_w); acc = x0[needed rows]
    init_x<<<2048, 256, 0, stream>>>(uw, iw, xA);
    gather_acc<true><<<(2 * BATCH * 16) / 256, 256, 0, stream>>>(user_ids, item_ids, xA, acc);

    float* xin = xA;
    float* xout = xB;
    for (int l = 0; l < 3; ++l) {
        hipMemsetAsync(xout, 0, xbytes, stream);
        spmm<<<2048, 256, 0, stream>>>(adj_row, adj_col, adj_val, xin, xout);
        gather_acc<false><<<(2 * BATCH * 16) / 256, 256, 0, stream>>>(user_ids, item_ids, xout, acc);
        float* tmp = xin; xin = xout; xout = tmp;
    }

    final_dot<<<(BATCH * 16) / 256, 256, 0, stream>>>(acc, out);
}

// Round 4
// 1074.747 us; speedup vs baseline: 9.6105x; 9.6105x over previous
//
#include <hip/hip_runtime.h>

#define NUM_USERS 100000
#define NUM_ITEMS 200000
#define NT        300000        // NUM_USERS + NUM_ITEMS
#define D         64
#define NNZ_C     4000000
#define BATCH     16384
#define SCAN_B    1024
#define NBLK_SCAN ((NT + SCAN_B - 1) / SCAN_B)   // 293

// ---------------------------------------------------------------------------
// init: x[r, :] = concat(user_emb_w, item_emb_w)[r, :]   (float4 vectorized)
// ---------------------------------------------------------------------------
__global__ void init_x(const float* __restrict__ uw, const float* __restrict__ iw,
                       float* __restrict__ x) {
    const long total = (long)NT * (D / 4);
    const long stride = (long)gridDim.x * blockDim.x;
    for (long i = (long)blockIdx.x * blockDim.x + threadIdx.x; i < total; i += stride) {
        long r = i >> 4;
        long c = i & 15;
        const float4* src = (r < NUM_USERS)
            ? (const float4*)uw + r * 16 + c
            : (const float4*)iw + (r - NUM_USERS) * 16 + c;
        ((float4*)x)[i] = *src;
    }
}

// ---------------------------------------------------------------------------
// CSR build: histogram -> block scan -> scan partials -> add offsets -> scatter
// ---------------------------------------------------------------------------
__global__ void hist_rows(const int* __restrict__ row, int* __restrict__ cnt) {
    int stride = gridDim.x * blockDim.x;
    for (int e = blockIdx.x * blockDim.x + threadIdx.x; e < NNZ_C; e += stride)
        atomicAdd(&cnt[row[e]], 1);
}

__global__ void scan_block(const int* __restrict__ cnt, int* __restrict__ rowstart,
                           int* __restrict__ partials) {
    __shared__ int s[SCAN_B];
    int tid = threadIdx.x;
    int idx = blockIdx.x * SCAN_B + tid;
    int v = (idx < NT) ? cnt[idx] : 0;
    int acc = v;
    s[tid] = acc;
    __syncthreads();
    for (int off = 1; off < SCAN_B; off <<= 1) {
        int t = (tid >= off) ? s[tid - off] : 0;
        __syncthreads();
        acc += t;
        s[tid] = acc;
        __syncthreads();
    }
    if (idx < NT) rowstart[idx] = acc - v;              // exclusive within block
    if (tid == SCAN_B - 1) partials[blockIdx.x] = acc;  // block total
}

__global__ void scan_partials(int* __restrict__ partials) {
    __shared__ int s[512];
    int tid = threadIdx.x;
    int v = (tid < NBLK_SCAN) ? partials[tid] : 0;
    int acc = v;
    s[tid] = acc;
    __syncthreads();
    for (int off = 1; off < 512; off <<= 1) {
        int t = (tid >= off) ? s[tid - off] : 0;
        __syncthreads();
        acc += t;
        s[tid] = acc;
        __syncthreads();
    }
    if (tid < NBLK_SCAN) partials[tid] = acc - v;       // exclusive block offsets
}

__global__ void add_offsets(int* __restrict__ rowstart, const int* __restrict__ partials) {
    int idx = blockIdx.x * SCAN_B + threadIdx.x;
    if (idx < NT) rowstart[idx] += partials[blockIdx.x];
    if (idx == 0) rowstart[NT] = NNZ_C;
}

__global__ void build_csr(const int* __restrict__ row, const int* __restrict__ col,
                          const float* __restrict__ val, int* __restrict__ cursor,
                          int2* __restrict__ cv) {
    int stride = gridDim.x * blockDim.x;
    for (int e = blockIdx.x * blockDim.x + threadIdx.x; e < NNZ_C; e += stride) {
        int r = row[e];
        int p = atomicAdd(&cursor[r], 1);
        cv[p] = make_int2(col[e], __float_as_int(val[e]));
    }
}

// ---------------------------------------------------------------------------
// CSR SpMM (gather): one 64-lane wave per row, lane = output dim.
// Per edge: wave-broadcast (col,val) + one coalesced 256B read of x[col].
// ---------------------------------------------------------------------------
__global__ void csr_spmm(const int* __restrict__ rowstart, const int2* __restrict__ cv,
                         const float* __restrict__ x, float* __restrict__ y) {
    int r = blockIdx.x * 4 + (threadIdx.x >> 6);
    int lane = threadIdx.x & 63;
    if (r >= NT) return;
    int s = rowstart[r], e = rowstart[r + 1];
    float a0 = 0.f, a1 = 0.f;
    int j = s;
    for (; j + 2 <= e; j += 2) {
        int2 c0 = cv[j], c1 = cv[j + 1];
        float x0 = x[(long)c0.x * D + lane];
        float x1 = x[(long)c1.x * D + lane];
        a0 += __int_as_float(c0.y) * x0;
        a1 += __int_as_float(c1.y) * x1;
    }
    if (j < e) {
        int2 c0 = cv[j];
        a0 += __int_as_float(c0.y) * x[(long)c0.x * D + lane];
    }
    y[(long)r * D + lane] = a0 + a1;
}

// ---------------------------------------------------------------------------
// Layer-3 SpMM only at the 2*BATCH needed rows, accumulated into acc.
// ---------------------------------------------------------------------------
__global__ void csr_spmm_acc(const int* __restrict__ uid, const int* __restrict__ iid,
                             const int* __restrict__ rowstart, const int2* __restrict__ cv,
                             const float* __restrict__ x, float* __restrict__ acc) {
    int b = blockIdx.x * 4 + (threadIdx.x >> 6);
    int lane = threadIdx.x & 63;
    if (b >= 2 * BATCH) return;
    int r = (b < BATCH) ? uid[b] : (iid[b - BATCH] + NUM_USERS);
    int s = rowstart[r], e = rowstart[r + 1];
    float a0 = 0.f, a1 = 0.f;
    int j = s;
    for (; j + 2 <= e; j += 2) {
        int2 c0 = cv[j], c1 = cv[j + 1];
        float x0 = x[(long)c0.x * D + lane];
        float x1 = x[(long)c1.x * D + lane];
        a0 += __int_as_float(c0.y) * x0;
        a1 += __int_as_float(c1.y) * x1;
    }
    if (j < e) {
        int2 c0 = cv[j];
        a0 += __int_as_float(c0.y) * x[(long)c0.x * D + lane];
    }
    acc[(long)b * D + lane] += a0 + a1;
}

// ---------------------------------------------------------------------------
// Fallback scatter SpMM (round-1 proven): 16 threads/edge, fp32 HW atomics.
// ---------------------------------------------------------------------------
__global__ void spmm_atomic(const int* __restrict__ row, const int* __restrict__ col,
                            const float* __restrict__ val, const float* __restrict__ x,
                            float* __restrict__ y) {
    const long total = (long)NNZ_C * 16;
    const long stride = (long)gridDim.x * blockDim.x;
    for (long t = (long)blockIdx.x * blockDim.x + threadIdx.x; t < total; t += stride) {
        long e   = t >> 4;
        int  sub = (int)(t & 15);
        int  r   = row[e];
        int  c   = col[e];
        float v  = val[e];
        float4 g = *(const float4*)(x + (long)c * D + sub * 4);
        float* yp = y + (long)r * D + sub * 4;
        unsafeAtomicAdd(yp + 0, g.x * v);
        unsafeAtomicAdd(yp + 1, g.y * v);
        unsafeAtomicAdd(yp + 2, g.z * v);
        unsafeAtomicAdd(yp + 3, g.w * v);
    }
}

// ---------------------------------------------------------------------------
// gather_acc: accumulate layer embedding at only the 2*BATCH needed rows.
// ---------------------------------------------------------------------------
template <bool FIRST>
__global__ void gather_acc(const int* __restrict__ uid, const int* __restrict__ iid,
                           const float* __restrict__ x, float* __restrict__ acc) {
    int t = blockIdx.x * blockDim.x + threadIdx.x;      // exact launch: 2*BATCH*16
    int b   = t >> 4;
    int sub = t & 15;
    int r   = (b < BATCH) ? uid[b] : (iid[b - BATCH] + NUM_USERS);
    float4 g = *(const float4*)(x + (long)r * D + sub * 4);
    float4* a = (float4*)(acc + (long)b * D) + sub;
    if (FIRST) {
        *a = g;
    } else {
        float4 p = *a;
        p.x += g.x; p.y += g.y; p.z += g.z; p.w += g.w;
        *a = p;
    }
}

// ---------------------------------------------------------------------------
// final: out[b] = dot(accU[b], accI[b]) / 16
// ---------------------------------------------------------------------------
__global__ void final_dot(const float* __restrict__ acc, float* __restrict__ out) {
    int t = blockIdx.x * blockDim.x + threadIdx.x;      // exact launch: BATCH*16
    int b   = t >> 4;
    int sub = t & 15;
    float4 u = *((const float4*)(acc + (long)b * D) + sub);
    float4 w = *((const float4*)(acc + (long)(b + BATCH) * D) + sub);
    float p = u.x * w.x + u.y * w.y + u.z * w.z + u.w * w.w;
    p += __shfl_xor(p, 1);
    p += __shfl_xor(p, 2);
    p += __shfl_xor(p, 4);
    p += __shfl_xor(p, 8);
    if (sub == 0) out[b] = p * (1.0f / 16.0f);
}

extern "C" void kernel_launch(void* const* d_in, const int* in_sizes, int n_in,
                              void* d_out, int out_size, void* d_ws, size_t ws_size,
                              hipStream_t stream) {
    const int*   user_ids = (const int*)d_in[0];
    const int*   item_ids = (const int*)d_in[1];
    const int*   adj_row  = (const int*)d_in[2];
    const int*   adj_col  = (const int*)d_in[3];
    const float* adj_val  = (const float*)d_in[4];
    const float* uw       = (const float*)d_in[5];
    const float* iw       = (const float*)d_in[6];
    float*       out      = (float*)d_out;

    // workspace bump allocator (256B aligned)
    char* ws = (char*)d_ws;
    size_t off = 0;
    auto alloc = [&](size_t bytes) {
        char* p = ws + off;
        off += (bytes + 255) & ~(size_t)255;
        return p;
    };
    const size_t xbytes = (size_t)NT * D * sizeof(float);                   // 76.8 MB
    float* xA  = (float*)alloc(xbytes);
    float* xB  = (float*)alloc(xbytes);
    float* acc = (float*)alloc((size_t)2 * BATCH * D * sizeof(float));      // 8.4 MB
    // CSR structures (only used on the fast path)
    size_t csr_base = off;
    int*   rowstart = (int*)alloc((size_t)(NT + 1) * sizeof(int));
    int*   cursor   = (int*)alloc((size_t)NT * sizeof(int));
    int*   partials = (int*)alloc(512 * sizeof(int));
    int2*  cv       = (int2*)alloc((size_t)NNZ_C * sizeof(int2));           // 32 MB
    const bool use_csr = (off <= ws_size);                                  // ~197 MB needed
    (void)csr_base;

    init_x<<<2048, 256, 0, stream>>>(uw, iw, xA);
    gather_acc<true><<<(2 * BATCH * 16) / 256, 256, 0, stream>>>(user_ids, item_ids, xA, acc);

    if (use_csr) {
        // ---- CSR build ----
        hipMemsetAsync(cursor, 0, (size_t)NT * sizeof(int), stream);        // reuse as cnt
        hist_rows<<<2048, 256, 0, stream>>>(adj_row, cursor);
        scan_block<<<NBLK_SCAN, SCAN_B, 0, stream>>>(cursor, rowstart, partials);
        scan_partials<<<1, 512, 0, stream>>>(partials);
        add_offsets<<<NBLK_SCAN, SCAN_B, 0, stream>>>(rowstart, partials);
        hipMemcpyAsync(cursor, rowstart, (size_t)NT * sizeof(int),
                       hipMemcpyDeviceToDevice, stream);
        build_csr<<<2048, 256, 0, stream>>>(adj_row, adj_col, adj_val, cursor, cv);

        // ---- layers ----
        csr_spmm<<<(NT + 3) / 4, 256, 0, stream>>>(rowstart, cv, xA, xB);   // layer 1
        gather_acc<false><<<(2 * BATCH * 16) / 256, 256, 0, stream>>>(user_ids, item_ids, xB, acc);

        csr_spmm<<<(NT + 3) / 4, 256, 0, stream>>>(rowstart, cv, xB, xA);   // layer 2
        gather_acc<false><<<(2 * BATCH * 16) / 256, 256, 0, stream>>>(user_ids, item_ids, xA, acc);

        // layer 3: only the 2*BATCH needed rows, straight into acc
        csr_spmm_acc<<<(2 * BATCH + 3) / 4, 256, 0, stream>>>(user_ids, item_ids,
                                                              rowstart, cv, xA, acc);
    } else {
        // ---- fallback: atomic scatter (fits in 162 MB, proven round 1) ----
        float* xin = xA;
        float* xout = xB;
        for (int l = 0; l < 3; ++l) {
            hipMemsetAsync(xout, 0, xbytes, stream);
            spmm_atomic<<<2048, 256, 0, stream>>>(adj_row, adj_col, adj_val, xin, xout);
            gather_acc<false><<<(2 * BATCH * 16) / 256, 256, 0, stream>>>(user_ids, item_ids, xout, acc);
            float* tmp = xin; xin = xout; xout = tmp;
        }
    }

    final_dot<<<(BATCH * 16) / 256, 256, 0, stream>>>(acc, out);
}